// Round 9
// baseline (294.865 us; speedup 1.0000x reference)
//
#include <hip/hip_runtime.h>

// StochasticRegionalConvolution — fused single-pass MFMA conv, vectorized staging.
// out[b,co,p,q] = coeff(p,q) * sum_{ci,kh,kw} x[b,ci,p+kh,q+kw] * W[co,ci,kh,kw]
//
// K1: coeff map (256x256 f32)                     -> d_ws[0, 256KB)
// K2: weight transform to MFMA A-frag order, bf16 -> d_ws[256KB, 328KB)
// K3: fused conv: 16x32 pixel tile, 512 thr / 8 waves, ALL 64 ci staged once:
//     LDS xs[612 pix][32 u32 ci-pairs] (78,336B -> 2 blk/CU), float4 staging
//     loads (4 px x 2 ci per task), XOR swizzle f=(pix^(pix>>2))&7 so B-frag
//     ds_read_b128 is ~conflict-free. One barrier pair. Epilogue: per-wave
//     ping-pong LDS slabs (overlaid on xs) -> full-128B-line float4 stores,
//     no block barriers.

typedef short short8 __attribute__((ext_vector_type(8)));
typedef float floatx4 __attribute__((ext_vector_type(4)));
typedef unsigned int uint4v __attribute__((ext_vector_type(4)));

#define OUTR 62

__device__ inline unsigned f2bf_pack(float lo, float hi) {
    unsigned ul = __builtin_bit_cast(unsigned, lo);
    unsigned uh = __builtin_bit_cast(unsigned, hi);
    ul = (ul + 0x7FFFu + ((ul >> 16) & 1u)) >> 16;   // RNE
    uh = (uh + 0x7FFFu + ((uh >> 16) & 1u)) >> 16;
    return ul | (uh << 16);
}

__global__ void srconv_coeff_kernel(const int* __restrict__ h_idx,
                                    const int* __restrict__ w_idx,
                                    const float* __restrict__ lam,
                                    int T, float* __restrict__ coeff) {
    int p = blockIdx.x;
    int q = threadIdx.x;
    float c = 0.f;
    for (int t = 0; t < T; ++t) {
        int dh = p - h_idx[t];
        int dw = q - w_idx[t];
        if (dh >= 0 && dh < OUTR && dw >= 0 && dw < OUTR) c += lam[t];
    }
    coeff[(p << 8) + q] = c * (1.0f / 16.0f);
}

__global__ void srconv_wtrans_kernel(const float* __restrict__ wgt,
                                     uint4v* __restrict__ afrag) {
    int id = blockIdx.x * 256 + threadIdx.x;      // [0, 72*64)
    int l  = id & 63;
    int fi = id >> 6;                             // (kk*2+cb)*4 + m
    int m  = fi & 3;
    int cb = (fi >> 2) & 1;
    int kk = fi >> 3;
    int co  = m * 16 + (l & 15);
    int ci0 = cb * 32 + (l >> 4) * 8;
    float w[8];
#pragma unroll
    for (int j = 0; j < 8; ++j)
        w[j] = wgt[(co * 64 + ci0 + j) * 9 + kk];
    uint4v d;
    d.x = f2bf_pack(w[0], w[1]);
    d.y = f2bf_pack(w[2], w[3]);
    d.z = f2bf_pack(w[4], w[5]);
    d.w = f2bf_pack(w[6], w[7]);
    afrag[id] = d;
}

// LDS layout: xs[pix][32 u32]; ci-pair cp lives at u32 slot
//   ((cp>>2) ^ f(pix))*4 + (cp&3),  f(pix) = (pix ^ (pix>>2)) & 7.
// B-frag (cb,kg) = b128 at slot16 = ((cb*4+kg) ^ f(pix)).
__launch_bounds__(512, 4)
__global__ void srconv_fused_kernel(const float* __restrict__ x,
                                    const float* __restrict__ coeff,
                                    const short8* __restrict__ afrag,
                                    float* __restrict__ out) {
    __shared__ __align__(16) unsigned xs[612 * 32];   // 78,336 B

    const int tid  = threadIdx.x;
    const int lane = tid & 63;
    const int wv   = tid >> 6;            // 0..7
    const int l15  = lane & 15;
    const int kg   = lane >> 4;

    // bijective XCD swizzle: 2048 blocks, 8 XCDs x 256 -> 2 batches per XCD
    const unsigned bid = blockIdx.x;
    const unsigned swz = (bid & 7) * 256 + (bid >> 3);
    const int b    = swz >> 7;
    const int tile = swz & 127;           // 16 p-tiles x 8 q-tiles
    const int P0   = (tile >> 3) << 4;
    const int Q0   = (tile & 7) << 5;

    // ---- tile skip vote ----
    float myc = coeff[((P0 + (tid >> 5)) << 8) + Q0 + (tid & 31)];
    if (__syncthreads_count(myc != 0.f) == 0) {
        const floatx4 z = (floatx4){0.f, 0.f, 0.f, 0.f};
        for (int u = tid; u < 64 * 16 * 8; u += 512) {
            int q4 = u & 7;
            int pr = (u >> 3) & 15;
            int co = u >> 7;
            *(floatx4*)(out + (((b << 6) + co) << 16) +
                        ((P0 + pr) << 8) + Q0 + (q4 << 2)) = z;
        }
        return;
    }

    const float* xb = x + ((size_t)b << 22);

    // ---- stage: 5184 tasks = 32 ci-pairs x 162 pixel-quads ----
    // task: 2 float4 loads (4 px, ci 2cp & 2cp+1) -> 4 packed u32 -> 4 b32 writes
    for (int u = tid; u < 5184; u += 512) {
        int cp    = u / 162;
        int quad  = u - cp * 162;
        int row   = quad / 9;
        int chunk = quad - row * 9;
        int gr    = min(P0 + row, 255);
        int gcb   = Q0 + (chunk << 2);
        if (gcb > 252) gcb = 252;         // edge: garbage feeds coeff==0 only
        const float* xp = xb + ((cp << 1) << 16) + (gr << 8) + gcb;
        const floatx4 v0 = *(const floatx4*)(xp);
        const floatx4 v1 = *(const floatx4*)(xp + 65536);
        const int c4   = chunk << 2;
        const int pixb = row * 34 + c4;
#pragma unroll
        for (int j = 0; j < 4; ++j) {
            if (c4 + j < 34) {
                int pix = pixb + j;
                int fp  = (pix ^ (pix >> 2)) & 7;
                xs[(pix << 5) + ((((cp >> 2) ^ fp) << 2) + (cp & 3))] =
                    f2bf_pack(v0[j], v1[j]);
            }
        }
    }
    __syncthreads();

    // ---- compute: 9 taps x 2 K-blocks, 16 MFMA each ----
    floatx4 acc[4][2][2];                 // [m: co16][p: row][h: q-half]
#pragma unroll
    for (int m = 0; m < 4; ++m)
#pragma unroll
        for (int p = 0; p < 2; ++p)
#pragma unroll
            for (int h = 0; h < 2; ++h)
                acc[m][p][h] = (floatx4){0.f, 0.f, 0.f, 0.f};

    const int prb = P0 + (wv << 1);

#pragma unroll
    for (int kk = 0; kk < 9; ++kk) {
        const int kh = kk / 3;
        const int kw = kk - kh * 3;
#pragma unroll
        for (int cb = 0; cb < 2; ++cb) {
            short8 a[4];
#pragma unroll
            for (int m = 0; m < 4; ++m)
                a[m] = afrag[((((kk << 1) + cb) << 2) + m) * 64 + lane];
            short8 bf[2][2];
#pragma unroll
            for (int p = 0; p < 2; ++p)
#pragma unroll
                for (int h = 0; h < 2; ++h) {
                    int prl = (wv << 1) + p + kh;          // 0..17
                    int cl  = (h << 4) + l15 + kw;         // 0..33
                    int pix = prl * 34 + cl;
                    int fp  = (pix ^ (pix >> 2)) & 7;
                    int off = (pix << 5) + (((((cb << 2) + kg) ^ fp)) << 2);
                    bf[p][h] = *(const short8*)(&xs[off]);
                }
#pragma unroll
            for (int m = 0; m < 4; ++m)
#pragma unroll
                for (int p = 0; p < 2; ++p)
#pragma unroll
                    for (int h = 0; h < 2; ++h)
                        acc[m][p][h] = __builtin_amdgcn_mfma_f32_16x16x32_bf16(
                            a[m], bf[p][h], acc[m][p][h], 0, 0, 0);
        }
    }
    __syncthreads();                      // all waves done reading xs

    // ---- epilogue: per-wave ping-pong slabs overlaid on xs, no block barriers
    // D layout (m89): col = lane&15 -> q, row = (lane>>4)*4+reg -> co-within-16
    float cf[2][2];
#pragma unroll
    for (int p = 0; p < 2; ++p)
#pragma unroll
        for (int h = 0; h < 2; ++h)
            cf[p][h] = coeff[((prb + p) << 8) + Q0 + (h << 4) + l15];

    float* epb = reinterpret_cast<float*>(xs);
    const int co_l = lane >> 3;           // 0..7
    const int q4   = lane & 7;

#pragma unroll
    for (int p = 0; p < 2; ++p) {
        const int pr = prb + p;
#pragma unroll
        for (int m = 0; m < 4; ++m) {
            float* ep = epb + (((wv << 1) + (m & 1)) * 576);
#pragma unroll
            for (int h = 0; h < 2; ++h)
#pragma unroll
                for (int reg = 0; reg < 4; ++reg)
                    ep[((kg << 2) + reg) * 36 + (h << 4) + l15] =
                        acc[m][p][h][reg] * cf[p][h];
            // wave-internal RAW through LDS: compiler-inserted lgkmcnt orders
#pragma unroll
            for (int j = 0; j < 2; ++j) {
                const floatx4 v = *reinterpret_cast<const floatx4*>(
                    &ep[(co_l + (j << 3)) * 36 + (q4 << 2)]);
                const int co = (m << 4) + co_l + (j << 3);
                *(floatx4*)(out + (((b << 6) + co) << 16) +
                            (pr << 8) + Q0 + (q4 << 2)) = v;
            }
        }
    }
}

extern "C" void kernel_launch(void* const* d_in, const int* in_sizes, int n_in,
                              void* d_out, int out_size, void* d_ws, size_t ws_size,
                              hipStream_t stream) {
    const float* x     = (const float*)d_in[0];
    const float* wgt   = (const float*)d_in[1];
    const int*   h_idx = (const int*)d_in[2];
    const int*   w_idx = (const int*)d_in[3];
    const float* lam   = (const float*)d_in[4];
    float*       out   = (float*)d_out;
    float*       coeff = (float*)d_ws;                        // 256 KB
    char*        af_b  = (char*)d_ws + 65536 * sizeof(float); // 72 KB
    const int    T     = in_sizes[2];

    srconv_coeff_kernel<<<256, 256, 0, stream>>>(h_idx, w_idx, lam, T, coeff);
    srconv_wtrans_kernel<<<18, 256, 0, stream>>>(wgt, (uint4v*)af_b);
    // 2048 blocks = 128 tiles x 16 batches, flattened + XCD-swizzled
    srconv_fused_kernel<<<2048, 512, 0, stream>>>(
        x, coeff, (const short8*)af_b, out);
}

// Round 10
// 210.328 us; speedup vs baseline: 1.4019x; 1.4019x over previous
//
#include <hip/hip_runtime.h>

// StochasticRegionalConvolution — fused MFMA conv, ILP-oriented build.
// out[b,co,p,q] = coeff(p,q) * sum_{ci,kh,kw} x[b,ci,p+kh,q+kw] * W[co,ci,kh,kw]
//
// K1: coeff map (256x256 f32)                     -> d_ws[0, 256KB)
// K2: weight transform to MFMA A-frag order, bf16 -> d_ws[256KB, 328KB)
// K3: fused conv: 8x32 pixel tile, 256 thr / 4 waves, two ci-half passes,
//     launch_bounds(256,3) -> ~170 reg budget: room for afrag prefetch
//     pipeline + deep staging loads. LDS 21.8KB. Barrier-free epilogue.

typedef short short8 __attribute__((ext_vector_type(8)));
typedef float floatx4 __attribute__((ext_vector_type(4)));
typedef unsigned int uint4v __attribute__((ext_vector_type(4)));

#define OUTR 62

__device__ inline unsigned f2bf_pack(float lo, float hi) {
    unsigned ul = __builtin_bit_cast(unsigned, lo);
    unsigned uh = __builtin_bit_cast(unsigned, hi);
    ul = (ul + 0x7FFFu + ((ul >> 16) & 1u)) >> 16;   // RNE
    uh = (uh + 0x7FFFu + ((uh >> 16) & 1u)) >> 16;
    return ul | (uh << 16);
}

__global__ void srconv_coeff_kernel(const int* __restrict__ h_idx,
                                    const int* __restrict__ w_idx,
                                    const float* __restrict__ lam,
                                    int T, float* __restrict__ coeff) {
    int p = blockIdx.x;
    int q = threadIdx.x;
    float c = 0.f;
    for (int t = 0; t < T; ++t) {
        int dh = p - h_idx[t];
        int dw = q - w_idx[t];
        if (dh >= 0 && dh < OUTR && dw >= 0 && dw < OUTR) c += lam[t];
    }
    coeff[(p << 8) + q] = c * (1.0f / 16.0f);
}

__global__ void srconv_wtrans_kernel(const float* __restrict__ wgt,
                                     uint4v* __restrict__ afrag) {
    int id = blockIdx.x * 256 + threadIdx.x;      // [0, 72*64)
    int l  = id & 63;
    int fi = id >> 6;                             // (kk*2+cb)*4 + m
    int m  = fi & 3;
    int cb = (fi >> 2) & 1;
    int kk = fi >> 3;
    int co  = m * 16 + (l & 15);
    int ci0 = cb * 32 + (l >> 4) * 8;
    float w[8];
#pragma unroll
    for (int j = 0; j < 8; ++j)
        w[j] = wgt[(co * 64 + ci0 + j) * 9 + kk];
    uint4v d;
    d.x = f2bf_pack(w[0], w[1]);
    d.y = f2bf_pack(w[2], w[3]);
    d.z = f2bf_pack(w[4], w[5]);
    d.w = f2bf_pack(w[6], w[7]);
    afrag[id] = d;
}

// LDS xs[pix 0..339][16 u32 ci-pairs], slot = cp ^ (((pix>>1)&3)<<2).
// B-frag (kg): b128 at slot base (kg<<2)^swz -> delivers ci 8kg..8kg+7 in order.
__launch_bounds__(256, 3)
__global__ void srconv_fused_kernel(const float* __restrict__ x,
                                    const float* __restrict__ coeff,
                                    const short8* __restrict__ afrag,
                                    float* __restrict__ out) {
    __shared__ __align__(16) unsigned xs[340 * 16];   // 21,760 B

    const int tid  = threadIdx.x;
    const int lane = tid & 63;
    const int wv   = tid >> 6;            // 0..3 -> p-rows {2wv, 2wv+1}
    const int l15  = lane & 15;
    const int kg   = lane >> 4;

    // bijective XCD swizzle: 4096 blocks, 8 XCDs x 512 -> 2 batches per XCD
    const unsigned bid = blockIdx.x;
    const unsigned swz = (bid & 7) * 512 + (bid >> 3);
    const int b    = swz >> 8;
    const int tile = swz & 255;           // 32 p-tiles x 8 q-tiles
    const int P0   = (tile >> 3) << 3;
    const int Q0   = (tile & 7) << 5;

    // ---- tile skip vote: 256 threads cover the 8x32 coeff tile ----
    float myc = coeff[((P0 + (tid >> 5)) << 8) + Q0 + (tid & 31)];
    if (__syncthreads_count(myc != 0.f) == 0) {
        const floatx4 z = (floatx4){0.f, 0.f, 0.f, 0.f};
        for (int u = tid; u < 64 * 8 * 8; u += 256) {
            int q4 = u & 7;
            int pr = (u >> 3) & 7;
            int co = u >> 6;
            *(floatx4*)(out + (((b << 6) + co) << 16) +
                        ((P0 + pr) << 8) + Q0 + (q4 << 2)) = z;
        }
        return;
    }

    floatx4 acc[4][2][2];                 // [m: co16][p: row][h: q-half]
#pragma unroll
    for (int m = 0; m < 4; ++m)
#pragma unroll
        for (int p = 0; p < 2; ++p)
#pragma unroll
            for (int h = 0; h < 2; ++h)
                acc[m][p][h] = (floatx4){0.f, 0.f, 0.f, 0.f};

    const float* xb  = x + ((size_t)b << 22);
    const int    prb = P0 + (wv << 1);

    for (int cb = 0; cb < 2; ++cb) {
        if (cb) __syncthreads();          // WAR: half0 reads done before restage
        // ---- stage ci-half: 1440 tasks = 16 ci-pairs x (10 rows x 9 chunks)
        // task: 2 float4 loads (4 px, 2 ci) -> 4 packed u32 -> 4 b32 writes
#pragma unroll
        for (int r = 0; r < 6; ++r) {
            int u  = r * 256 + tid;
            int uc = u < 1440 ? u : 1439;
            int cp    = uc / 90;
            int rem   = uc - cp * 90;
            int row   = rem / 9;
            int chunk = rem - row * 9;
            int gr    = min(P0 + row, 255);
            int gcb   = min(Q0 + (chunk << 2), 252);
            const float* xp = xb + (((cb << 4) + cp) << 17) + (gr << 8) + gcb;
            const floatx4 v0 = *(const floatx4*)(xp);
            const floatx4 v1 = *(const floatx4*)(xp + 65536);
            const int c4   = chunk << 2;
#pragma unroll
            for (int j = 0; j < 4; ++j) {
                if (u < 1440 && c4 + j < 34) {
                    int pix = row * 34 + c4 + j;
                    int slot = cp ^ (((pix >> 1) & 3) << 2);
                    xs[(pix << 4) + slot] = f2bf_pack(v0[j], v1[j]);
                }
            }
        }
        __syncthreads();

        // ---- compute: 9 taps, A-frag prefetch pipeline ----
        const short8* af = afrag + (cb << 8);     // + cb*256
        short8 a_cur[4];
#pragma unroll
        for (int m = 0; m < 4; ++m)
            a_cur[m] = af[(m << 6) + lane];       // kk = 0
#pragma unroll
        for (int kk = 0; kk < 9; ++kk) {
            const int kh = kk / 3;
            const int kw = kk - kh * 3;
            short8 a_nxt[4];
            if (kk < 8) {
                const short8* afn = af + ((kk + 1) << 9);
#pragma unroll
                for (int m = 0; m < 4; ++m)
                    a_nxt[m] = afn[(m << 6) + lane];
            }
            short8 bf[2][2];
#pragma unroll
            for (int p = 0; p < 2; ++p)
#pragma unroll
                for (int h = 0; h < 2; ++h) {
                    int prl = (wv << 1) + p + kh;          // 0..9
                    int cl  = (h << 4) + l15 + kw;         // 0..33
                    int pix = prl * 34 + cl;
                    int off = (pix << 4) +
                              ((kg << 2) ^ (((pix >> 1) & 3) << 2));
                    bf[p][h] = *(const short8*)(&xs[off]);
                }
#pragma unroll
            for (int m = 0; m < 4; ++m)
#pragma unroll
                for (int p = 0; p < 2; ++p)
#pragma unroll
                    for (int h = 0; h < 2; ++h)
                        acc[m][p][h] = __builtin_amdgcn_mfma_f32_16x16x32_bf16(
                            a_cur[m], bf[p][h], acc[m][p][h], 0, 0, 0);
            if (kk < 8) {
#pragma unroll
                for (int m = 0; m < 4; ++m) a_cur[m] = a_nxt[m];
            }
        }
    }
    __syncthreads();                      // all waves done reading xs

    // ---- epilogue: per-wave ping-pong slabs overlaid on xs, no barriers
    // D layout (m89): col = lane&15 -> q, row = (lane>>4)*4+reg -> co-within-16
    float cf[2][2];
#pragma unroll
    for (int p = 0; p < 2; ++p)
#pragma unroll
        for (int h = 0; h < 2; ++h)
            cf[p][h] = coeff[((prb + p) << 8) + Q0 + (h << 4) + l15];

    float* epb = reinterpret_cast<float*>(xs);
    const int co_l = lane >> 3;           // 0..7
    const int q4   = lane & 7;

#pragma unroll
    for (int p = 0; p < 2; ++p) {
        const int pr = prb + p;
#pragma unroll
        for (int m = 0; m < 4; ++m) {
            float* ep = epb + (((wv << 1) + (m & 1)) * 576);
#pragma unroll
            for (int h = 0; h < 2; ++h)
#pragma unroll
                for (int reg = 0; reg < 4; ++reg)
                    ep[((kg << 2) + reg) * 36 + (h << 4) + l15] =
                        acc[m][p][h][reg] * cf[p][h];
            // wave-internal RAW through LDS: compiler-inserted lgkmcnt orders
#pragma unroll
            for (int j = 0; j < 2; ++j) {
                const floatx4 v = *reinterpret_cast<const floatx4*>(
                    &ep[(co_l + (j << 3)) * 36 + (q4 << 2)]);
                const int co = (m << 4) + co_l + (j << 3);
                *(floatx4*)(out + (((b << 6) + co) << 16) +
                            (pr << 8) + Q0 + (q4 << 2)) = v;
            }
        }
    }
}

extern "C" void kernel_launch(void* const* d_in, const int* in_sizes, int n_in,
                              void* d_out, int out_size, void* d_ws, size_t ws_size,
                              hipStream_t stream) {
    const float* x     = (const float*)d_in[0];
    const float* wgt   = (const float*)d_in[1];
    const int*   h_idx = (const int*)d_in[2];
    const int*   w_idx = (const int*)d_in[3];
    const float* lam   = (const float*)d_in[4];
    float*       out   = (float*)d_out;
    float*       coeff = (float*)d_ws;                        // 256 KB
    char*        af_b  = (char*)d_ws + 65536 * sizeof(float); // 72 KB
    const int    T     = in_sizes[2];

    srconv_coeff_kernel<<<256, 256, 0, stream>>>(h_idx, w_idx, lam, T, coeff);
    srconv_wtrans_kernel<<<18, 256, 0, stream>>>(wgt, (uint4v*)af_b);
    // 4096 blocks = (32 p-tiles x 8 q-tiles) x 16 batches, XCD-swizzled
    srconv_fused_kernel<<<4096, 256, 0, stream>>>(
        x, coeff, (const short8*)af_b, out);
}